// Round 1
// baseline (767.113 us; speedup 1.0000x reference)
//
#include <hip/hip_runtime.h>

#define N_NODES 50000
#define N_EDGES 800000
#define N_GRAPHS 128
#define JK 576              // 64 + 256 + 256
#define CAP 192             // reverted 96->192: single-variable A/B on lp regression
#define NSB ((N_NODES + 255) / 256)   // scan blocks = 196

typedef __attribute__((ext_vector_type(8))) short bf16x8;
typedef __attribute__((ext_vector_type(4))) float f32x4;

// ---------- bf16 pack/unpack helpers ----------
__device__ __forceinline__ unsigned f2_to_bf2(float a, float b) {
    unsigned ua = __float_as_uint(a), ub = __float_as_uint(b);
    ua = (ua + 0x7fffu + ((ua >> 16) & 1u)) >> 16;       // RNE
    ub = (ub + 0x7fffu + ((ub >> 16) & 1u)) >> 16;
    return ua | (ub << 16);
}
__device__ __forceinline__ uint2 f4_to_bf4(float4 v) {
    return make_uint2(f2_to_bf2(v.x, v.y), f2_to_bf2(v.z, v.w));
}
__device__ __forceinline__ float4 bf4_to_f4(uint2 u) {
    float4 r;
    r.x = __uint_as_float(u.x << 16);
    r.y = __uint_as_float(u.x & 0xffff0000u);
    r.z = __uint_as_float(u.y << 16);
    r.w = __uint_as_float(u.y & 0xffff0000u);
    return r;
}

// ---------- MFMA GEMM: bf16 out = A_bf16 @ B (BT n-major bf16), fp32 acc ----------
template<int BN, int KK>
__global__ __launch_bounds__(256)
void mfma_gemm(const unsigned short* __restrict__ Abf, int lda,
               const unsigned short* __restrict__ BT,
               unsigned* __restrict__ Cbf, int ldc,
               int M, const float* __restrict__ bias, int relu,
               int a_off, int b_off, int c_off) {
    __shared__ unsigned short As[64][32];
    __shared__ unsigned short Bs[BN][32];
    const int t = threadIdx.x;
    const int wav = t >> 6, lane = t & 63;
    const int quad = lane >> 4, l15 = lane & 15;
    const int m0 = blockIdx.x * 64;
    const int head = blockIdx.y;
    Abf += (size_t)head * a_off;
    BT  += (size_t)head * b_off;
    const float* bptr = bias ? bias + (size_t)head * c_off : nullptr;
    unsigned* cbf = Cbf + (((size_t)head * c_off) >> 1);

    f32x4 acc[BN / 16];
#pragma unroll
    for (int i = 0; i < BN / 16; i++) acc[i] = (f32x4){0.f, 0.f, 0.f, 0.f};

    const int arow = t >> 2, aseg = t & 3;
    for (int k0 = 0; k0 < KK; k0 += 32) {
        uint4 av = make_uint4(0, 0, 0, 0);
        int gm = m0 + arow;
        if (gm < M) av = *(const uint4*)&Abf[(size_t)gm * lda + k0 + aseg * 8];
        uint4 bv[BN == 256 ? 4 : 1];
        if (BN == 256) {
            const unsigned short* srcb = &BT[(size_t)t * KK + k0];
#pragma unroll
            for (int j = 0; j < 4; j++) bv[j] = *(const uint4*)&srcb[j * 8];
        } else {
            bv[0] = *(const uint4*)&BT[(size_t)arow * KK + k0 + aseg * 8];
        }
        __syncthreads();
        *(uint4*)&As[arow][aseg * 8] = av;
        if (BN == 256) {
#pragma unroll
            for (int j = 0; j < 4; j++) *(uint4*)&Bs[t][j * 8] = bv[j];
        } else {
            *(uint4*)&Bs[arow][aseg * 8] = bv[0];
        }
        __syncthreads();
        bf16x8 afrag = *(const bf16x8*)&As[wav * 16 + l15][quad * 8];
#pragma unroll
        for (int nt = 0; nt < BN / 16; nt++) {
            bf16x8 bfrag = *(const bf16x8*)&Bs[nt * 16 + l15][quad * 8];
            acc[nt] = __builtin_amdgcn_mfma_f32_16x16x32_bf16(afrag, bfrag, acc[nt], 0, 0, 0);
        }
    }
    int rbase = m0 + wav * 16 + quad * 4;
#pragma unroll
    for (int nt = 0; nt < BN / 16; nt++) {
        int col = nt * 16 + l15;
        float bb = bptr ? bptr[col] : 0.f;
#pragma unroll
        for (int r = 0; r < 4; r++) {
            int row = rbase + r;
            float v = acc[nt][r] + bb;
            if (relu) v = fmaxf(v, 0.f);
            float vp = __shfl_xor(v, 1);
            if (row < M && !(l15 & 1))
                cbf[((size_t)row * ldc + col) >> 1] = f2_to_bf2(v, vp);
        }
    }
}

// ---------- degree + graph bounds (fused) ----------
__global__ void deg_kernel(const int* __restrict__ dst, int* __restrict__ deg,
                           const int* __restrict__ batch, int* __restrict__ gstart) {
    int t = blockIdx.x * blockDim.x + threadIdx.x;
    if (t < N_EDGES) {
        atomicAdd(&deg[dst[t]], 1);
    } else if (t < N_EDGES + N_NODES) {
        int n = t - N_EDGES;
        int b = batch[n];
        int prev = (n == 0) ? -1 : batch[n - 1];
        for (int g = prev + 1; g <= b; g++) gstart[g] = n;
        if (n == N_NODES - 1)
            for (int g = b + 1; g <= N_GRAPHS; g++) gstart[g] = N_NODES;
    }
}

// ---- fused misc prep: dis | prep_w1 | prep_w2 | W1T | W2T | xbf | pool(x) ----
#define S1 50000
#define S2 50256
#define S3 51280
#define S4 67664
#define S5 133200
#define S6 1733200            // S5 + 50000*32  (xbf pairs)
#define S7 (S6 + 131072)      // + 128 graphs * 4 quarters * 256 threads (x pooling)
__global__ void prep_misc(const int* __restrict__ deg, float* __restrict__ dis,
                          const float* __restrict__ W1, const float* __restrict__ a1s,
                          const float* __restrict__ a1d, float* __restrict__ wes1,
                          float* __restrict__ wed1,
                          const float* __restrict__ W2, const float* __restrict__ a2s,
                          const float* __restrict__ a2d, float* __restrict__ wes2,
                          float* __restrict__ wed2,
                          unsigned short* __restrict__ W1T, unsigned short* __restrict__ W2T,
                          const float* __restrict__ x, unsigned* __restrict__ xbf,
                          const int* __restrict__ gstart, float* __restrict__ psum) {
    int i = blockIdx.x * blockDim.x + threadIdx.x;
    if (i >= S7) return;
    if (i >= S6) {                       // pool x -> psum[:, 0:64]
        int t2 = i - S6;
        int g = t2 >> 10, rem = t2 & 1023;
        int q = rem >> 8, tid = rem & 255;
        int cp = tid & 63, np = tid >> 6;
        int n0 = gstart[g], n1 = gstart[g + 1];
        int len = n1 - n0;
        int ns = n0 + (len * q) / 4, ne = n0 + (len * (q + 1)) / 4;
        float s = 0.f;
        for (int n = ns + np; n < ne; n += 4) s += x[(size_t)n * 64 + cp];
        atomicAdd(&psum[g * JK + cp], s);
    } else if (i >= S5) {                // x -> bf16 (pairs)
        int j = i - S5;
        float2 v = *(const float2*)&x[(size_t)j * 2];
        xbf[j] = f2_to_bf2(v.x, v.y);
    } else if (i >= S4) {                // W2T
        int t2 = i - S4;
        int n = t2 >> 8, c = t2 & 255;
        unsigned u = __float_as_uint(W2[(size_t)c * 256 + n]);
        u = (u + 0x7fffu + ((u >> 16) & 1u)) >> 16;
        W2T[t2] = (unsigned short)u;
    } else if (i >= S3) {                // W1T
        int t2 = i - S3;
        int n = t2 >> 6, c = t2 & 63;
        unsigned u = __float_as_uint(W1[(size_t)c * 256 + n]);
        u = (u + 0x7fffu + ((u >> 16) & 1u)) >> 16;
        W1T[t2] = (unsigned short)u;
    } else if (i >= S2) {                // prep_w2
        int t2 = i - S2;
        int c = t2 >> 2, h = t2 & 3;
        float se = 0.f, sd = 0.f;
        for (int j = 0; j < 64; j++) {
            float w = W2[(size_t)c * 256 + h * 64 + j];
            se += w * a2s[h * 64 + j];
            sd += w * a2d[h * 64 + j];
        }
        wes2[c * 4 + h] = se;
        wed2[c * 4 + h] = sd;
    } else if (i >= S1) {                // prep_w1
        int t2 = i - S1;
        int c = t2 >> 2, h = t2 & 3;
        float se = 0.f, sd = 0.f;
        for (int j = 0; j < 64; j++) {
            float w = W1[(size_t)c * 256 + h * 64 + j];
            se += w * a1s[h * 64 + j];
            sd += w * a1d[h * 64 + j];
        }
        wes1[c * 4 + h] = se;
        wed1[c * 4 + h] = sd;
    } else {                             // dis
        int d = deg[i];
        dis[i] = d > 0 ? rsqrtf((float)d) : 0.f;
    }
}
// ---- hierarchical scan ----
__global__ __launch_bounds__(256) void scan_bsum(const int* __restrict__ deg,
                                                 int* __restrict__ bsum) {
    __shared__ int sd[256];
    int n = blockIdx.x * 256 + threadIdx.x;
    sd[threadIdx.x] = (n < N_NODES) ? deg[n] : 0;
    __syncthreads();
    for (int o = 128; o > 0; o >>= 1) {
        if (threadIdx.x < o) sd[threadIdx.x] += sd[threadIdx.x + o];
        __syncthreads();
    }
    if (threadIdx.x == 0) bsum[blockIdx.x] = sd[0];
}
__global__ __launch_bounds__(256) void scan_bpre(const int* __restrict__ bsum,
                                                 int* __restrict__ bpre,
                                                 int* __restrict__ off_last) {
    __shared__ int sd[256];
    int t = threadIdx.x;
    int v = (t < NSB) ? bsum[t] : 0;
    sd[t] = v;
    __syncthreads();
    for (int o = 1; o < 256; o <<= 1) {
        int u = (t >= o) ? sd[t - o] : 0;
        __syncthreads();
        sd[t] += u;
        __syncthreads();
    }
    if (t < NSB) bpre[t] = sd[t] - v;
    if (t == 255) *off_last = sd[255];
}
__global__ __launch_bounds__(256) void scan_off(const int* __restrict__ deg,
                                                const int* __restrict__ bpre,
                                                int* __restrict__ off) {
    __shared__ int sd[256];
    int n = blockIdx.x * 256 + threadIdx.x;
    int t = threadIdx.x;
    int v = (n < N_NODES) ? deg[n] : 0;
    sd[t] = v;
    __syncthreads();
    for (int o = 1; o < 256; o <<= 1) {
        int u = (t >= o) ? sd[t - o] : 0;
        __syncthreads();
        sd[t] += u;
        __syncthreads();
    }
    if (n < N_NODES) off[n] = bpre[blockIdx.x] + sd[t] - v;
}
__global__ void csr_fill(const int* __restrict__ src, const int* __restrict__ dst,
                         const int* __restrict__ off, int* __restrict__ cursor,
                         int* __restrict__ csr_src) {
    int e = blockIdx.x * blockDim.x + threadIdx.x;
    if (e >= N_EDGES) return;
    int s = src[e], d = dst[e];
    int pos = off[d] + atomicAdd(&cursor[d], 1);
    csr_src[pos] = s;
}

// ---------- es/ed from K=64 fp32 input (x) ----------
__global__ void esed_x(const float* __restrict__ X, const float* __restrict__ wes,
                       const float* __restrict__ wed, float* __restrict__ es,
                       float* __restrict__ ed) {
    int gid = blockIdx.x * blockDim.x + threadIdx.x;
    int n = gid >> 6, lane = threadIdx.x & 63;
    if (n >= N_NODES) return;
    float xv = X[(size_t)n * 64 + lane];
    float4 a = *(const float4*)&wes[lane * 4];
    float4 b = *(const float4*)&wed[lane * 4];
    float4 ps = make_float4(xv * a.x, xv * a.y, xv * a.z, xv * a.w);
    float4 pd = make_float4(xv * b.x, xv * b.y, xv * b.z, xv * b.w);
#pragma unroll
    for (int o = 1; o < 64; o <<= 1) {
        ps.x += __shfl_xor(ps.x, o); ps.y += __shfl_xor(ps.y, o);
        ps.z += __shfl_xor(ps.z, o); ps.w += __shfl_xor(ps.w, o);
        pd.x += __shfl_xor(pd.x, o); pd.y += __shfl_xor(pd.y, o);
        pd.z += __shfl_xor(pd.z, o); pd.w += __shfl_xor(pd.w, o);
    }
    if (lane == 0) {
        *(float4*)&es[n * 4] = ps;
        *(float4*)&ed[n * 4] = pd;
    }
}

// ---------- GAT1: fused softmax + bf16-x aggregation (depth-4 pipeline) ----------
__global__ __launch_bounds__(256)
void gat1_fused(const int* __restrict__ off, const int* __restrict__ csr_src,
                const float* __restrict__ es, const float* __restrict__ ed,
                const unsigned* __restrict__ xbf, unsigned* __restrict__ aggx_bf,
                float* __restrict__ alpha_fb) {
    __shared__ float elds[4][CAP * 4];
    __shared__ int   sidx[4][CAP];
    int wav = threadIdx.x >> 6, lane = threadIdx.x & 63;
    int n = blockIdx.x * 4 + wav;
    bool active = n < N_NODES;
    int p0 = 0, p1 = 0;
    float4 ed4 = make_float4(0.f, 0.f, 0.f, 0.f);
    if (active) { p0 = off[n]; p1 = off[n + 1]; ed4 = *(const float4*)&ed[n * 4]; }
    float4 sum = make_float4(0.f, 0.f, 0.f, 0.f);
    for (int p = p0 + lane; p < p1; p += 64) {
        int s = csr_src[p];
        float4 e4 = *(const float4*)&es[s * 4];
        e4.x += ed4.x; e4.y += ed4.y; e4.z += ed4.z; e4.w += ed4.w;
        e4.x = e4.x > 0.f ? e4.x : 0.2f * e4.x;
        e4.y = e4.y > 0.f ? e4.y : 0.2f * e4.y;
        e4.z = e4.z > 0.f ? e4.z : 0.2f * e4.z;
        e4.w = e4.w > 0.f ? e4.w : 0.2f * e4.w;
        e4.x = __expf(e4.x); e4.y = __expf(e4.y); e4.z = __expf(e4.z); e4.w = __expf(e4.w);
        int q = p - p0;
        if (q < CAP) { *(float4*)&elds[wav][q * 4] = e4; sidx[wav][q] = s; }
        else         *(float4*)&alpha_fb[(size_t)p * 4] = e4;
        sum.x += e4.x; sum.y += e4.y; sum.z += e4.z; sum.w += e4.w;
    }
#pragma unroll
    for (int o = 1; o < 64; o <<= 1) {
        sum.x += __shfl_xor(sum.x, o); sum.y += __shfl_xor(sum.y, o);
        sum.z += __shfl_xor(sum.z, o); sum.w += __shfl_xor(sum.w, o);
    }
    float4 rs;
    rs.x = sum.x > 0.f ? 1.f / sum.x : 0.f;
    rs.y = sum.y > 0.f ? 1.f / sum.y : 0.f;
    rs.z = sum.z > 0.f ? 1.f / sum.z : 0.f;
    rs.w = sum.w > 0.f ? 1.f / sum.w : 0.f;
    if (!active) return;
    int eg = lane >> 4, l15 = lane & 15;
    int deg = p1 - p0;
    float4 a0 = make_float4(0.f, 0.f, 0.f, 0.f);
    float4 a1 = a0, a2 = a0, a3 = a0;
    auto fetch = [&](int qq, float4& e4, float4& xv) {
        e4 = make_float4(0.f, 0.f, 0.f, 0.f);
        xv = e4;
        if (qq < deg) {
            int s;
            if (qq < CAP) { s = sidx[wav][qq]; e4 = *(const float4*)&elds[wav][qq * 4]; }
            else { s = csr_src[p0 + qq]; e4 = *(const float4*)&alpha_fb[(size_t)(p0 + qq) * 4]; }
            xv = bf4_to_f4(*(const uint2*)&xbf[(size_t)s * 32 + l15 * 2]);
        }
    };
    int q = eg;
    float4 eA, xA, eB, xB, eC, xC;
    fetch(q, eA, xA);
    fetch(q + 4, eB, xB);
    fetch(q + 8, eC, xC);
    while (q < deg) {
        float4 eD, xD;
        fetch(q + 12, eD, xD);
        a0.x += eA.x * xA.x; a0.y += eA.x * xA.y; a0.z += eA.x * xA.z; a0.w += eA.x * xA.w;
        a1.x += eA.y * xA.x; a1.y += eA.y * xA.y; a1.z += eA.y * xA.z; a1.w += eA.y * xA.w;
        a2.x += eA.z * xA.x; a2.y += eA.z * xA.y; a2.z += eA.z * xA.z; a2.w += eA.z * xA.w;
        a3.x += eA.w * xA.x; a3.y += eA.w * xA.y; a3.z += eA.w * xA.z; a3.w += eA.w * xA.w;
        eA = eB; xA = xB; eB = eC; xB = xC; eC = eD; xC = xD;
        q += 4;
    }
#pragma unroll
    for (int o = 16; o < 64; o <<= 1) {
        a0.x += __shfl_xor(a0.x, o); a0.y += __shfl_xor(a0.y, o);
        a0.z += __shfl_xor(a0.z, o); a0.w += __shfl_xor(a0.w, o);
        a1.x += __shfl_xor(a1.x, o); a1.y += __shfl_xor(a1.y, o);
        a1.z += __shfl_xor(a1.z, o); a1.w += __shfl_xor(a1.w, o);
        a2.x += __shfl_xor(a2.x, o); a2.y += __shfl_xor(a2.y, o);
        a2.z += __shfl_xor(a2.z, o); a2.w += __shfl_xor(a2.w, o);
        a3.x += __shfl_xor(a3.x, o); a3.y += __shfl_xor(a3.y, o);
        a3.z += __shfl_xor(a3.z, o); a3.w += __shfl_xor(a3.w, o);
    }
    if (eg == 0) {
        a0.x *= rs.x; a0.y *= rs.x; a0.z *= rs.x; a0.w *= rs.x;
        a1.x *= rs.y; a1.y *= rs.y; a1.z *= rs.y; a1.w *= rs.y;
        a2.x *= rs.z; a2.y *= rs.z; a2.z *= rs.z; a2.w *= rs.z;
        a3.x *= rs.w; a3.y *= rs.w; a3.z *= rs.w; a3.w *= rs.w;
        size_t b = (size_t)n * 128 + l15 * 2;
        *(uint2*)&aggx_bf[b +  0] = f4_to_bf4(a0);
        *(uint2*)&aggx_bf[b + 32] = f4_to_bf4(a1);
        *(uint2*)&aggx_bf[b + 64] = f4_to_bf4(a2);
        *(uint2*)&aggx_bf[b + 96] = f4_to_bf4(a3);
    }
}

// ---------- GAT2: fused softmax + bf16 gather (depth-4 pipeline) ----------
__global__ __launch_bounds__(256)
void gat2_fused(const int* __restrict__ off, const int* __restrict__ csr_src,
                const float* __restrict__ es, const float* __restrict__ ed,
                const unsigned* __restrict__ H2bf, const float* __restrict__ bias,
                unsigned* __restrict__ outbf, float* __restrict__ alpha_fb) {
    __shared__ float elds[4][CAP * 4];
    __shared__ int   sidx[4][CAP];
    int wav = threadIdx.x >> 6, lane = threadIdx.x & 63;
    int n = blockIdx.x * 4 + wav;
    bool active = n < N_NODES;
    int p0 = 0, p1 = 0;
    float4 ed4 = make_float4(0.f, 0.f, 0.f, 0.f);
    if (active) { p0 = off[n]; p1 = off[n + 1]; ed4 = *(const float4*)&ed[n * 4]; }
    float4 sum = make_float4(0.f, 0.f, 0.f, 0.f);
    for (int p = p0 + lane; p < p1; p += 64) {
        int s = csr_src[p];
        float4 e4 = *(const float4*)&es[s * 4];
        e4.x += ed4.x; e4.y += ed4.y; e4.z += ed4.z; e4.w += ed4.w;
        e4.x = e4.x > 0.f ? e4.x : 0.2f * e4.x;
        e4.y = e4.y > 0.f ? e4.y : 0.2f * e4.y;
        e4.z = e4.z > 0.f ? e4.z : 0.2f * e4.z;
        e4.w = e4.w > 0.f ? e4.w : 0.2f * e4.w;
        e4.x = __expf(e4.x); e4.y = __expf(e4.y); e4.z = __expf(e4.z); e4.w = __expf(e4.w);
        int q = p - p0;
        if (q < CAP) { *(float4*)&elds[wav][q * 4] = e4; sidx[wav][q] = s; }
        else         *(float4*)&alpha_fb[(size_t)p * 4] = e4;
        sum.x += e4.x; sum.y += e4.y; sum.z += e4.z; sum.w += e4.w;
    }
#pragma unroll
    for (int o = 1; o < 64; o <<= 1) {
        sum.x += __shfl_xor(sum.x, o); sum.y += __shfl_xor(sum.y, o);
        sum.z += __shfl_xor(sum.z, o); sum.w += __shfl_xor(sum.w, o);
    }
    if (!active) return;
    int half = lane >> 5, l = lane & 31;
    int hh = l >> 3;
    float sh = (hh == 0) ? sum.x : (hh == 1) ? sum.y : (hh == 2) ? sum.z : sum.w;
    float rsh = sh > 0.f ? 1.f / sh : 0.f;
    int deg = p1 - p0;
    float acc[8];
#pragma unroll
    for (int j = 0; j < 8; j++) acc[j] = 0.f;
    auto fetch = [&](int qq, float& al, uint4& rr) {
        al = 0.f;
        rr = make_uint4(0, 0, 0, 0);
        if (qq < deg) {
            int s;
            if (qq < CAP) { s = sidx[wav][qq]; al = elds[wav][qq * 4 + hh]; }
            else { s = csr_src[p0 + qq]; al = alpha_fb[(size_t)(p0 + qq) * 4 + hh]; }
            rr = *(const uint4*)&H2bf[(size_t)s * 128 + l * 4];
        }
    };
    int q = half;
    float aA, aB, aC;
    uint4 rA, rB, rC;
    fetch(q, aA, rA);
    fetch(q + 2, aB, rB);
    fetch(q + 4, aC, rC);
    while (q < deg) {
        float aD; uint4 rD;
        fetch(q + 6, aD, rD);
        float4 f0 = bf4_to_f4(make_uint2(rA.x, rA.y));
        float4 f1 = bf4_to_f4(make_uint2(rA.z, rA.w));
        acc[0] += aA * f0.x; acc[1] += aA * f0.y; acc[2] += aA * f0.z; acc[3] += aA * f0.w;
        acc[4] += aA * f1.x; acc[5] += aA * f1.y; acc[6] += aA * f1.z; acc[7] += aA * f1.w;
        aA = aB; rA = rB; aB = aC; rB = rC; aC = aD; rC = rD;
        q += 2;
    }
#pragma unroll
    for (int j = 0; j < 8; j++) acc[j] += __shfl_xor(acc[j], 32);
    if (half == 0) {
        float4 b0 = *(const float4*)&bias[l * 8];
        float4 b1 = *(const float4*)&bias[l * 8 + 4];
        float4 o0, o1;
        o0.x = fmaxf(acc[0] * rsh + b0.x, 0.f);
        o0.y = fmaxf(acc[1] * rsh + b0.y, 0.f);
        o0.z = fmaxf(acc[2] * rsh + b0.z, 0.f);
        o0.w = fmaxf(acc[3] * rsh + b0.w, 0.f);
        o1.x = fmaxf(acc[4] * rsh + b1.x, 0.f);
        o1.y = fmaxf(acc[5] * rsh + b1.y, 0.f);
        o1.z = fmaxf(acc[6] * rsh + b1.z, 0.f);
        o1.w = fmaxf(acc[7] * rsh + b1.w, 0.f);
        uint2 w0 = f4_to_bf4(o0), w1 = f4_to_bf4(o1);
        uint4 w = make_uint4(w0.x, w0.y, w1.x, w1.y);
        *(uint4*)&outbf[(size_t)n * 128 + l * 4] = w;
    }
}

// ---------- label prop: LDS staging, depth-4 pipeline; optional fused esed ----------
template<int FUSE_ESED>
__global__ __launch_bounds__(256)
void lp_csr_t(const int* __restrict__ off, const int* __restrict__ csr_src,
              const float* __restrict__ dis, const unsigned* __restrict__ in_bf,
              const unsigned* __restrict__ res_bf, unsigned* __restrict__ out_bf,
              const float* __restrict__ wes, const float* __restrict__ wed,
              float* __restrict__ es, float* __restrict__ ed) {
    __shared__ int   widx[4][CAP];
    __shared__ float wwt[4][CAP];
    int wav = threadIdx.x >> 6, lane = threadIdx.x & 63;
    int n = blockIdx.x * 4 + wav;
    if (n >= N_NODES) return;
    int p0 = off[n], p1 = off[n + 1];
    int deg = p1 - p0;
    float disd = dis[n];
    for (int q = lane; q < deg && q < CAP; q += 64) {
        int s = csr_src[p0 + q];
        widx[wav][q] = s;
        wwt[wav][q] = dis[s] * disd;
    }
    int half = lane >> 5, l = lane & 31;
    float acc[8];
#pragma unroll
    for (int j = 0; j < 8; j++) acc[j] = 0.f;
    auto fetch = [&](int qq, float& nw, uint4& rr) {
        nw = 0.f;
        rr = make_uint4(0, 0, 0, 0);
        if (qq < deg) {
            int s;
            if (qq < CAP) { s = widx[wav][qq]; nw = wwt[wav][qq]; }
            else { s = csr_src[p0 + qq]; nw = dis[s] * disd; }
            rr = *(const uint4*)&in_bf[(size_t)s * 128 + l * 4];
        }
    };
    int q = half;
    float nA, nB, nC;
    uint4 rA, rB, rC;
    fetch(q, nA, rA);
    fetch(q + 2, nB, rB);
    fetch(q + 4, nC, rC);
    while (q < deg) {
        float nD; uint4 rD;
        fetch(q + 6, nD, rD);
        float4 f0 = bf4_to_f4(make_uint2(rA.x, rA.y));
        float4 f1 = bf4_to_f4(make_uint2(rA.z, rA.w));
        acc[0] += nA * f0.x; acc[1] += nA * f0.y; acc[2] += nA * f0.z; acc[3] += nA * f0.w;
        acc[4] += nA * f1.x; acc[5] += nA * f1.y; acc[6] += nA * f1.z; acc[7] += nA * f1.w;
        nA = nB; rA = rB; nB = nC; rB = rC; nC = nD; rC = rD;
        q += 2;
    }
#pragma unroll
    for (int j = 0; j < 8; j++) acc[j] += __shfl_xor(acc[j], 32);
    if (half == 0) {
        uint4 rr = *(const uint4*)&res_bf[(size_t)n * 128 + l * 4];
        float4 r0 = bf4_to_f4(make_uint2(rr.x, rr.y));
        float4 r1 = bf4_to_f4(make_uint2(rr.z, rr.w));
        float4 o0, o1;
        o0.x = fminf(fmaxf(0.5f * acc[0] + 0.5f * r0.x, 0.f), 1.f);
        o0.y = fminf(fmaxf(0.5f * acc[1] + 0.5f * r0.y, 0.f), 1.f);
        o0.z = fminf(fmaxf(0.5f * acc[2] + 0.5f * r0.z, 0.f), 1.f);
        o0.w = fminf(fmaxf(0.5f * acc[3] + 0.5f * r0.w, 0.f), 1.f);
        o1.x = fminf(fmaxf(0.5f * acc[4] + 0.5f * r1.x, 0.f), 1.f);
        o1.y = fminf(fmaxf(0.5f * acc[5] + 0.5f * r1.y, 0.f), 1.f);
        o1.z = fminf(fmaxf(0.5f * acc[6] + 0.5f * r1.z, 0.f), 1.f);
        o1.w = fminf(fmaxf(0.5f * acc[7] + 0.5f * r1.w, 0.f), 1.f);
        uint2 w0 = f4_to_bf4(o0), w1 = f4_to_bf4(o1);
        uint4 w = make_uint4(w0.x, w0.y, w1.x, w1.y);
        *(uint4*)&out_bf[(size_t)n * 128 + l * 4] = w;
        if (FUSE_ESED) {
            float vv[8] = {o0.x, o0.y, o0.z, o0.w, o1.x, o1.y, o1.z, o1.w};
            float4 ps = make_float4(0.f, 0.f, 0.f, 0.f);
            float4 pd = make_float4(0.f, 0.f, 0.f, 0.f);
#pragma unroll
            for (int j = 0; j < 8; j++) {
                int c = l * 8 + j;
                float4 a = *(const float4*)&wes[c * 4];
                float4 b = *(const float4*)&wed[c * 4];
                ps.x += vv[j] * a.x; ps.y += vv[j] * a.y; ps.z += vv[j] * a.z; ps.w += vv[j] * a.w;
                pd.x += vv[j] * b.x; pd.y += vv[j] * b.y; pd.z += vv[j] * b.z; pd.w += vv[j] * b.w;
            }
#pragma unroll
            for (int o = 1; o < 32; o <<= 1) {
                ps.x += __shfl_xor(ps.x, o); ps.y += __shfl_xor(ps.y, o);
                ps.z += __shfl_xor(ps.z, o); ps.w += __shfl_xor(ps.w, o);
                pd.x += __shfl_xor(pd.x, o); pd.y += __shfl_xor(pd.y, o);
                pd.z += __shfl_xor(pd.z, o); pd.w += __shfl_xor(pd.w, o);
            }
            if (l == 0) {
                *(float4*)&es[n * 4] = ps;
                *(float4*)&ed[n * 4] = pd;
            }
        }
    }
}

// ---------- bf16 pool ----------
__global__ void pool_bf(const unsigned* __restrict__ buf, const int* __restrict__ gstart,
                        float* __restrict__ psum, int colOff) {
    int g = blockIdx.x, q = blockIdx.y;
    int n0 = gstart[g], n1 = gstart[g + 1];
    int len = n1 - n0;
    int ns = n0 + (len * q) / 4, ne = n0 + (len * (q + 1)) / 4;
    int cp = threadIdx.x & 127;
    int np = threadIdx.x >> 7;
    float s0 = 0.f, s1 = 0.f;
    for (int n = ns + np; n < ne; n += 2) {
        unsigned u = buf[(size_t)n * 128 + cp];
        s0 += __uint_as_float(u << 16);
        s1 += __uint_as_float(u & 0xffff0000u);
    }
    atomicAdd(&psum[g * JK + colOff + cp * 2 + 0], s0);
    atomicAdd(&psum[g * JK + colOff + cp * 2 + 1], s1);
}

// ---------- full MLP head: one block per graph ----------
__global__ __launch_bounds__(256)
void head_all(const float* __restrict__ psum, const int* __restrict__ gstart,
              const float* __restrict__ clin,
              const float* __restrict__ pp_w1, const float* __restrict__ pp_b1,
              const float* __restrict__ pp_w2, const float* __restrict__ pp_b2,
              const float* __restrict__ cl_w1, const float* __restrict__ cl_b1,
              const float* __restrict__ cl_w2, const float* __restrict__ cl_b2,
              const float* __restrict__ h_w1, const float* __restrict__ h_b1,
              const float* __restrict__ h_w2, const float* __restrict__ h_b2,
              const float* __restrict__ h_w3, const float* __restrict__ h_b3,
              float* __restrict__ out) {
    __shared__ float zin[JK];
    __shared__ float z1[256];
    __shared__ float zcl[32];
    __shared__ float zc[64];
    __shared__ float z[160];
    __shared__ float z3[64];
    __shared__ float z4[32];
    __shared__ float part[128];
    int g = blockIdx.x, t = threadIdx.x;
    int len = gstart[g + 1] - gstart[g];
    float inv = 1.f / (float)(len > 1 ? len : 1);
    for (int k = t; k < JK; k += 256) zin[k] = psum[g * JK + k] * inv;
    if (t < 32) zcl[t] = clin[g * 32 + t];
    __syncthreads();
    {
        float acc = pp_b1[t];
#pragma unroll 8
        for (int k = 0; k < JK; k++) acc += zin[k] * pp_w1[k * 256 + t];
        z1[t] = fmaxf(acc, 0.f);
    }
    __syncthreads();
    int m = t & 127, half = t >> 7;
    {
        float acc = 0.f;
        int k0 = half * 128;
#pragma unroll 8
        for (int k = k0; k < k0 + 128; k++) acc += z1[k] * pp_w2[k * 128 + m];
        if (half) part[m] = acc;
        __syncthreads();
        if (!half) z[m] = acc + part[m] + pp_b2[m];
    }
    if (t < 64) {
        float acc = cl_b1[t];
#pragma unroll
        for (int k = 0; k < 32; k++) acc += zcl[k] * cl_w1[k * 64 + t];
        zc[t] = fmaxf(acc, 0.f);
    }
    __syncthreads();
    if (t < 32) {
        float acc = cl_b2[t];
#pragma unroll
        for (int k = 0; k < 64; k++) acc += zc[k] * cl_w2[k * 32 + t];
        z[128 + t] = acc;
    }
    __syncthreads();
    if (t < 64) {
        float acc = h_b1[t];
#pragma unroll 8
        for (int k = 0; k < 160; k++) acc += z[k] * h_w1[k * 64 + t];
        z3[t] = fmaxf(acc, 0.f);
    }
    __syncthreads();
    if (t < 32) {
        float acc = h_b2[t];
#pragma unroll
        for (int k = 0; k < 64; k++) acc += z3[k] * h_w2[k * 32 + t];
        z4[t] = fmaxf(acc, 0.f);
    }
    __syncthreads();
    if (t < 2) {
        float acc = h_b3[t];
#pragma unroll
        for (int k = 0; k < 32; k++) acc += z4[k] * h_w3[k * 2 + t];
        out[g * 2 + t] = acc;
    }
}

// ---------- launch ----------
extern "C" void kernel_launch(void* const* d_in, const int* in_sizes, int n_in,
                              void* d_out, int out_size, void* d_ws, size_t ws_size,
                              hipStream_t stream) {
    const float* x     = (const float*)d_in[0];
    const int*   ei    = (const int*)d_in[1];
    const int*   batch = (const int*)d_in[2];
    const float* clin  = (const float*)d_in[3];
    const float* W1  = (const float*)d_in[4];
    const float* a1s = (const float*)d_in[5];
    const float* a1d = (const float*)d_in[6];
    const float* b1  = (const float*)d_in[7];
    const float* W2  = (const float*)d_in[8];
    const float* a2s = (const float*)d_in[9];
    const float* a2d = (const float*)d_in[10];
    const float* b2  = (const float*)d_in[11];
    const float* pp_w1 = (const float*)d_in[12];
    const float* pp_b1 = (const float*)d_in[13];
    const float* pp_w2 = (const float*)d_in[14];
    const float* pp_b2 = (const float*)d_in[15];
    const float* cl_w1 = (const float*)d_in[16];
    const float* cl_b1 = (const float*)d_in[17];
    const float* cl_w2 = (const float*)d_in[18];
    const float* cl_b2 = (const float*)d_in[19];
    const float* h_w1  = (const float*)d_in[20];
    const float* h_b1  = (const float*)d_in[21];
    const float* h_w2  = (const float*)d_in[22];
    const float* h_b2  = (const float*)d_in[23];
    const float* h_w3  = (const float*)d_in[24];
    const float* h_b3  = (const float*)d_in[25];

    const int* src = ei;
    const int* dst = ei + N_EDGES;

    char* p = (char*)d_ws;
    auto carve = [&](size_t bytes) -> char* {
        char* r = p;
        p += (bytes + 255) & ~(size_t)255;
        return r;
    };
    const size_t NBH = (size_t)N_NODES * 256 * 2;    // bf16 node buffer
    unsigned* abf  = (unsigned*)carve(NBH);          // aggx, later h2_final
    unsigned* bf1  = (unsigned*)carve(NBH);
    unsigned* bf2  = (unsigned*)carve(NBH);
    unsigned* bf3  = (unsigned*)carve(NBH);
    unsigned* xbf  = (unsigned*)carve((size_t)N_NODES * 32 * 4);  // bf16 x copy
    float* alpha_fb  = (float*)carve((size_t)N_EDGES * 4 * 4);
    int*   csr_src   = (int*)carve((size_t)N_EDGES * 4);
    int*   off       = (int*)carve((size_t)(N_NODES + 1) * 4);
    int*   deg       = (int*)carve((size_t)N_NODES * 4);
    int*   cursor    = (int*)carve((size_t)N_NODES * 4);
    int*   bsum      = (int*)carve((size_t)NSB * 4);
    int*   bpre      = (int*)carve((size_t)NSB * 4);
    float* dis       = (float*)carve((size_t)N_NODES * 4);
    float* es        = (float*)carve((size_t)N_NODES * 4 * 4);
    float* ed        = (float*)carve((size_t)N_NODES * 4 * 4);
    float* wes1      = (float*)carve((size_t)64 * 4 * 4);
    float* wed1      = (float*)carve((size_t)64 * 4 * 4);
    float* wes2      = (float*)carve((size_t)256 * 4 * 4);
    float* wed2      = (float*)carve((size_t)256 * 4 * 4);
    unsigned short* W1T = (unsigned short*)carve((size_t)256 * 64 * 2);
    unsigned short* W2T = (unsigned short*)carve((size_t)256 * 256 * 2);
    int*   gstart    = (int*)carve((size_t)(N_GRAPHS + 1) * 4);
    float* psum      = (float*)carve((size_t)N_GRAPHS * JK * 4);

    const int TB = 256;
    const int gE     = (N_EDGES + TB - 1) / TB;
    const int gDeg   = (N_EDGES + N_NODES + TB - 1) / TB;
    const int gNwave = (N_NODES * 64 + TB - 1) / TB;
    const int gFuse  = (N_NODES + 3) / 4;
    const int gRow   = (N_NODES + 63) / 64;
    const int gPrep  = (S7 + TB - 1) / TB;

    // ---- CSR + degree + bounds + fused misc prep (incl. x pooling) ----
    hipMemsetAsync(deg, 0, (size_t)N_NODES * 4, stream);
    hipMemsetAsync(cursor, 0, (size_t)N_NODES * 4, stream);
    hipMemsetAsync(psum, 0, (size_t)N_GRAPHS * JK * 4, stream);
    deg_kernel<<<gDeg, TB, 0, stream>>>(dst, deg, batch, gstart);
    prep_misc<<<gPrep, TB, 0, stream>>>(deg, dis,
                                        W1, a1s, a1d, wes1, wed1,
                                        W2, a2s, a2d, wes2, wed2,
                                        W1T, W2T, x, xbf, gstart, psum);
    scan_bsum<<<NSB, 256, 0, stream>>>(deg, bsum);
    scan_bpre<<<1, 256, 0, stream>>>(bsum, bpre, &off[N_NODES]);
    scan_off<<<NSB, 256, 0, stream>>>(deg, bpre, off);
    csr_fill<<<gE, TB, 0, stream>>>(src, dst, off, cursor, csr_src);

    // ---- GAT layer 1 ----
    esed_x<<<gNwave, TB, 0, stream>>>(x, wes1, wed1, es, ed);
    gat1_fused<<<gFuse, TB, 0, stream>>>(off, csr_src, es, ed, xbf, abf, alpha_fb);
    mfma_gemm<64, 64><<<dim3(gRow, 4), 256, 0, stream>>>(
        (const unsigned short*)abf, 256, W1T, bf1, 256, N_NODES, b1, 1,
        64, 64 * 64, 64);                                   // bf1 = h1a

    // ---- label prop 1 (residual = bf1); 2nd step fuses esed for layer 2 ----
    lp_csr_t<0><<<gFuse, TB, 0, stream>>>(off, csr_src, dis, bf1, bf1, bf2,
                                          nullptr, nullptr, nullptr, nullptr);
    lp_csr_t<1><<<gFuse, TB, 0, stream>>>(off, csr_src, dis, bf2, bf1, bf3,
                                          wes2, wed2, es, ed);   // bf3 = h1, es/ed ready

    pool_bf<<<dim3(N_GRAPHS, 4), TB, 0, stream>>>(bf3, gstart, psum, 64);

    // ---- GAT layer 2 ----
    mfma_gemm<256, 256><<<dim3(gRow, 1), 256, 0, stream>>>(
        (const unsigned short*)bf3, 256, W2T, bf1, 256, N_NODES, nullptr, 0,
        0, 0, 0);                                           // bf1 = h2
    gat2_fused<<<gFuse, TB, 0, stream>>>(off, csr_src, es, ed, bf1, b2, bf2, alpha_fb); // bf2 = h2a

    // ---- label prop 2 (residual = bf2) ----
    lp_csr_t<0><<<gFuse, TB, 0, stream>>>(off, csr_src, dis, bf2, bf2, bf1,
                                          nullptr, nullptr, nullptr, nullptr);
    lp_csr_t<0><<<gFuse, TB, 0, stream>>>(off, csr_src, dis, bf1, bf2, abf,
                                          nullptr, nullptr, nullptr, nullptr);  // abf = h2_final

    // ---- pooling (h2) + full head ----
    pool_bf<<<dim3(N_GRAPHS, 4), TB, 0, stream>>>(abf, gstart, psum, 320);
    head_all<<<N_GRAPHS, 256, 0, stream>>>(psum, gstart, clin,
                                           pp_w1, pp_b1, pp_w2, pp_b2,
                                           cl_w1, cl_b1, cl_w2, cl_b2,
                                           h_w1, h_b1, h_w2, h_b2, h_w3, h_b3,
                                           (float*)d_out);
}